// Round 2
// baseline (1188.527 us; speedup 1.0000x reference)
//
#include <hip/hip_runtime.h>
#include <hip/hip_bf16.h>

// MultiHeadAttentionBlock: B=4,S=2048,D=1024,H=16,DQ=64
// out[b,h,s,:] = diag_softmax_weight(b,h,s) * V[b,h,s,:]   (fp32 output)
// Workspace layout (~103 MB):
//   Qw, Kw, Vw : [B,H,S,DQ] fp32 (33.5 MB each)
//   bits       : packed mask, [B*S][S/32] uint32 (2 MB)

#define BB 4
#define SS 2048
#define DD 1024
#define HH 16
#define DQQ 64

static constexpr float SCALE = 0.125f;   // 1/sqrt(64)
static constexpr float NEGINF_SCORE = -1e9f;

// ---------------- mask bit-pack ----------------
__global__ __launch_bounds__(256) void mask_pack_k(const int* __restrict__ mask,
                                                   unsigned int* __restrict__ bits) {
    const int w = blockIdx.x * 256 + threadIdx.x;            // 0 .. B*S*64-1
    const long long row  = (long long)(w >> 6);              // b*S+s
    const long long base = row * SS + (long long)((w & 63) << 5);
    const int4* mp = reinterpret_cast<const int4*>(mask + base);
    unsigned int v = 0;
#pragma unroll
    for (int j = 0; j < 8; ++j) {
        int4 m4 = mp[j];
        v |= (m4.x != 0 ? 1u : 0u) << (4 * j + 0);
        v |= (m4.y != 0 ? 1u : 0u) << (4 * j + 1);
        v |= (m4.z != 0 ? 1u : 0u) << (4 * j + 2);
        v |= (m4.w != 0 ? 1u : 0u) << (4 * j + 3);
    }
    bits[w] = v;
}

// ---------------- projection GEMM ----------------
// Out[b,h,s,q] = sum_d X[b,s,d] * W[h,d,q]   (fp32, tile 64x64, K-chunk 32)
__global__ __launch_bounds__(256) void proj_k(const float* __restrict__ X,
                                              const float* __restrict__ W,
                                              float* __restrict__ Out) {
    const int s0 = blockIdx.x * 64, h = blockIdx.y, b = blockIdx.z;
    __shared__ float Xs[32][64];   // [kk][row]  (transposed for b128 reads)
    __shared__ float Ws[32][64];   // [kk][col]
    const int t = threadIdx.x, tr = t >> 4, tc = t & 15;
    const float* Xb = X + (long long)(b * SS + s0) * DD;
    const float* Wb = W + (long long)h * (DD * DQQ);
    const int xs = t >> 2, xk = (t & 3) * 8;       // X staging: row xs, kk xk..xk+7
    const int wq = t & 63, wk = (t >> 6) * 8;      // W staging: col wq, kk wk..wk+7
    float acc[4][4] = {};
    for (int k0 = 0; k0 < DD; k0 += 32) {
        __syncthreads();
        float4 a0 = *reinterpret_cast<const float4*>(Xb + (long long)xs * DD + k0 + xk);
        float4 a1 = *reinterpret_cast<const float4*>(Xb + (long long)xs * DD + k0 + xk + 4);
        Xs[xk + 0][xs] = a0.x; Xs[xk + 1][xs] = a0.y; Xs[xk + 2][xs] = a0.z; Xs[xk + 3][xs] = a0.w;
        Xs[xk + 4][xs] = a1.x; Xs[xk + 5][xs] = a1.y; Xs[xk + 6][xs] = a1.z; Xs[xk + 7][xs] = a1.w;
#pragma unroll
        for (int j = 0; j < 8; ++j)
            Ws[wk + j][wq] = Wb[(long long)(k0 + wk + j) * DQQ + wq];
        __syncthreads();
#pragma unroll
        for (int kk = 0; kk < 32; ++kk) {
            float xa[4], wv[4];
            *reinterpret_cast<float4*>(xa) = *reinterpret_cast<const float4*>(&Xs[kk][tr * 4]);
            *reinterpret_cast<float4*>(wv) = *reinterpret_cast<const float4*>(&Ws[kk][tc * 4]);
#pragma unroll
            for (int i = 0; i < 4; ++i)
#pragma unroll
                for (int j = 0; j < 4; ++j)
                    acc[i][j] = fmaf(xa[i], wv[j], acc[i][j]);
        }
    }
    float* Ob = Out + ((long long)(b * HH + h) * SS + s0) * DQQ;
#pragma unroll
    for (int i = 0; i < 4; ++i) {
        float4 o = make_float4(acc[i][0], acc[i][1], acc[i][2], acc[i][3]);
        *reinterpret_cast<float4*>(Ob + (long long)(tr * 4 + i) * DQQ + tc * 4) = o;
    }
}

// ---------------- scores + online softmax diag + output ----------------
// One block per (b,h,s-tile of 64). Iterates all t in chunks of 64.
__global__ __launch_bounds__(256) void attn_k(const float* __restrict__ Qw,
                                              const float* __restrict__ Kw,
                                              const float* __restrict__ Vw,
                                              const unsigned int* __restrict__ bits,
                                              float* __restrict__ out) {
    const int s0 = blockIdx.x * 64, h = blockIdx.y, b = blockIdx.z;
    __shared__ float Qs[64][64];   // [dq][row]
    __shared__ float Ks[64][64];   // [dq][t]
    __shared__ float sdiag[64];
    __shared__ float dwgt[64];
    const int t = threadIdx.x, tr = t >> 4, tc = t & 15;
    const long long bh = (long long)(b * HH + h);
    const float* Qb = Qw + (bh * SS + s0) * DQQ;
    const float* Kb = Kw + bh * SS * DQQ;
    const int rr = t >> 2, c0 = (t & 3) * 16;   // staging: row rr, dq c0..c0+15

    // stage Q transposed (once)
#pragma unroll
    for (int j = 0; j < 16; j += 4) {
        float4 v = *reinterpret_cast<const float4*>(Qb + (long long)rr * DQQ + c0 + j);
        Qs[c0 + j + 0][rr] = v.x; Qs[c0 + j + 1][rr] = v.y;
        Qs[c0 + j + 2][rr] = v.z; Qs[c0 + j + 3][rr] = v.w;
    }

    float m[4], sum[4];
#pragma unroll
    for (int i = 0; i < 4; ++i) { m[i] = -INFINITY; sum[i] = 0.f; }

    for (int cch = 0; cch < SS / 64; ++cch) {
        const int t0 = cch * 64;
        __syncthreads();
#pragma unroll
        for (int j = 0; j < 16; j += 4) {
            float4 v = *reinterpret_cast<const float4*>(Kb + (long long)(t0 + rr) * DQQ + c0 + j);
            Ks[c0 + j + 0][rr] = v.x; Ks[c0 + j + 1][rr] = v.y;
            Ks[c0 + j + 2][rr] = v.z; Ks[c0 + j + 3][rr] = v.w;
        }
        __syncthreads();

        float sc[4][4] = {};
#pragma unroll 8
        for (int dq = 0; dq < 64; ++dq) {
            float xa[4], kv[4];
            *reinterpret_cast<float4*>(xa) = *reinterpret_cast<const float4*>(&Qs[dq][tr * 4]);
            *reinterpret_cast<float4*>(kv) = *reinterpret_cast<const float4*>(&Ks[dq][tc * 4]);
#pragma unroll
            for (int i = 0; i < 4; ++i)
#pragma unroll
                for (int j = 0; j < 4; ++j)
                    sc[i][j] = fmaf(xa[i], kv[j], sc[i][j]);
        }

        const int tg = t0 + tc * 4;
#pragma unroll
        for (int i = 0; i < 4; ++i) {
            const int srow = s0 + tr * 4 + i;
            const unsigned int wb =
                bits[((long long)b * SS + srow) * 64 + (tg >> 5)] >> (tg & 31);
            float v[4];
#pragma unroll
            for (int j = 0; j < 4; ++j)
                v[j] = ((wb >> j) & 1u) ? sc[i][j] * SCALE : NEGINF_SCORE;
            if (cch == blockIdx.x && tc == tr) sdiag[tr * 4 + i] = v[i];
            float vmax = fmaxf(fmaxf(v[0], v[1]), fmaxf(v[2], v[3]));
            float nm = fmaxf(m[i], vmax);
            float s4 = __expf(v[0] - nm) + __expf(v[1] - nm) +
                       __expf(v[2] - nm) + __expf(v[3] - nm);
            sum[i] = sum[i] * __expf(m[i] - nm) + s4;
            m[i] = nm;
        }
    }

    // merge (m,sum) across the 16 lanes sharing each row group
#pragma unroll
    for (int st = 1; st < 16; st <<= 1) {
#pragma unroll
        for (int i = 0; i < 4; ++i) {
            float om = __shfl_xor(m[i], st, 64);
            float os = __shfl_xor(sum[i], st, 64);
            float nm = fmaxf(m[i], om);
            sum[i] = sum[i] * __expf(m[i] - nm) + os * __expf(om - nm);
            m[i] = nm;
        }
    }
    __syncthreads();   // sdiag visibility
    if (tc == 0) {
#pragma unroll
        for (int i = 0; i < 4; ++i)
            dwgt[tr * 4 + i] = __expf(sdiag[tr * 4 + i] - m[i]) / sum[i];
    }
    __syncthreads();

    // output: out[b,h,s0+rr, :] = dwgt[rr] * V row  (fp32)
    const float* Vb = Vw + (bh * SS + s0) * DQQ;
    const float dw = dwgt[rr];
    float* op = out + (bh * SS + s0 + rr) * DQQ + c0;
#pragma unroll
    for (int j = 0; j < 16; j += 4) {
        float4 v = *reinterpret_cast<const float4*>(Vb + (long long)rr * DQQ + c0 + j);
        float4 o = make_float4(v.x * dw, v.y * dw, v.z * dw, v.w * dw);
        *reinterpret_cast<float4*>(op + j) = o;
    }
}

extern "C" void kernel_launch(void* const* d_in, const int* in_sizes, int n_in,
                              void* d_out, int out_size, void* d_ws, size_t ws_size,
                              hipStream_t stream) {
    (void)in_sizes; (void)n_in; (void)out_size; (void)ws_size;
    const float* q    = (const float*)d_in[0];
    const float* k    = (const float*)d_in[1];
    const float* v    = (const float*)d_in[2];
    const int*   mask = (const int*)d_in[3];
    const float* wq   = (const float*)d_in[4];
    const float* wk   = (const float*)d_in[5];
    const float* wv   = (const float*)d_in[6];

    const size_t NPROJ = (size_t)BB * HH * SS * DQQ;   // 8388608
    float* Qw = (float*)d_ws;
    float* Kw = Qw + NPROJ;
    float* Vw = Kw + NPROJ;
    unsigned int* bits = (unsigned int*)(Vw + NPROJ);  // B*S*64 words

    mask_pack_k<<<dim3((BB * SS * 64) / 256), dim3(256), 0, stream>>>(mask, bits);

    dim3 g(SS / 64, HH, BB);
    proj_k<<<g, dim3(256), 0, stream>>>(q, wq, Qw);
    proj_k<<<g, dim3(256), 0, stream>>>(k, wk, Kw);
    proj_k<<<g, dim3(256), 0, stream>>>(v, wv, Vw);

    attn_k<<<g, dim3(256), 0, stream>>>(Qw, Kw, Vw, bits, (float*)d_out);
}

// Round 3
// 349.608 us; speedup vs baseline: 3.3996x; 3.3996x over previous
//
#include <hip/hip_runtime.h>

// MultiHeadAttentionBlock: B=4,S=2048,D=1024,H=16,DQ=64
// out[b,h,s,:] = diag_softmax_weight(b,h,s) * V[b,h,s,:]   (fp32 output)
// Split-bf16 (hi=trunc, lo=RNE(residual)) 3-product MFMA for Q/K path,
// plain bf16 MFMA for V. Scores fp32-accurate to ~1e-2 absolute.
//
// Workspace (~94 MB):
//   Qh,Ql,Kh,Kl : [B,H,S,DQ] u16   (16.78 MB each)
//   Vb          : [B,H,S,DQ] u16   (16.78 MB)
//   Wt_hi,Wt_lo : [3][H][DQ][D] u16 (6.29 MB each; lo of z=2 unused)
//   bits        : [B*S][S/32] u32  (2.1 MB)

#define BB 4
#define SS 2048
#define DD 1024
#define HH 16
#define DQQ 64

typedef unsigned short u16;
typedef unsigned int u32;
typedef __attribute__((ext_vector_type(8))) short bf16x8;
typedef __attribute__((ext_vector_type(4))) float f32x4;

static constexpr float SCALE = 0.125f;   // 1/sqrt(64)
static constexpr float NEG9 = -1e9f;

__device__ __forceinline__ u16 bfrne(float x) {
    u32 u = __float_as_uint(x);
    return (u16)((u + 0x7fffu + ((u >> 16) & 1u)) >> 16);
}

#define MFMA16(a, b, c) __builtin_amdgcn_mfma_f32_16x16x32_bf16((a), (b), (c), 0, 0, 0)

// ---------------- mask bit-pack ----------------
__global__ __launch_bounds__(256) void mask_pack_k(const int* __restrict__ mask,
                                                   u32* __restrict__ bits) {
    const int w = blockIdx.x * 256 + threadIdx.x;            // 0 .. B*S*64-1
    const long long row  = (long long)(w >> 6);              // b*S+s
    const long long base = row * SS + (long long)((w & 63) << 5);
    const int4* mp = reinterpret_cast<const int4*>(mask + base);
    u32 v = 0;
#pragma unroll
    for (int j = 0; j < 8; ++j) {
        int4 m4 = mp[j];
        v |= (m4.x != 0 ? 1u : 0u) << (4 * j + 0);
        v |= (m4.y != 0 ? 1u : 0u) << (4 * j + 1);
        v |= (m4.z != 0 ? 1u : 0u) << (4 * j + 2);
        v |= (m4.w != 0 ? 1u : 0u) << (4 * j + 3);
    }
    bits[w] = v;
}

// ---------------- W transpose + split ----------------
// W[h][d][q] fp32 -> Wt_hi/lo[z][h][q][d] u16
__global__ __launch_bounds__(256) void wsplit_k(const float* __restrict__ wq,
                                                const float* __restrict__ wk,
                                                const float* __restrict__ wv,
                                                u16* __restrict__ Wt_hi,
                                                u16* __restrict__ Wt_lo) {
    const int d0 = blockIdx.x * 64, h = blockIdx.y, z = blockIdx.z;
    const float* W = (z == 0) ? wq : ((z == 1) ? wk : wv);
    __shared__ float Wl[64][65];
    const int t = threadIdx.x;
    {
        const int r = t >> 2, qi = (t & 3) * 16;
        const float* src = W + ((long long)(h * DD) + d0 + r) * DQQ + qi;
#pragma unroll
        for (int j = 0; j < 4; ++j) {
            float4 v4 = reinterpret_cast<const float4*>(src)[j];
            Wl[r][qi + 4 * j + 0] = v4.x; Wl[r][qi + 4 * j + 1] = v4.y;
            Wl[r][qi + 4 * j + 2] = v4.z; Wl[r][qi + 4 * j + 3] = v4.w;
        }
    }
    __syncthreads();
    const int qq = t >> 2, di = (t & 3) * 16;
    u16 hb[16], lb[16];
#pragma unroll
    for (int j = 0; j < 16; ++j) {
        float x = Wl[di + j][qq];
        u32 u = __float_as_uint(x);
        hb[j] = (u16)(u >> 16);
        float rres = x - __uint_as_float(u & 0xFFFF0000u);
        lb[j] = bfrne(rres);
    }
    const long long base = ((long long)(z * HH + h) * DQQ + qq) * DD + d0 + di;
#pragma unroll
    for (int j = 0; j < 2; ++j)
        reinterpret_cast<uint4*>(&Wt_hi[base])[j] = reinterpret_cast<uint4*>(hb)[j];
    if (z < 2) {
#pragma unroll
        for (int j = 0; j < 2; ++j)
            reinterpret_cast<uint4*>(&Wt_lo[base])[j] = reinterpret_cast<uint4*>(lb)[j];
    }
}

// ---------------- projection GEMM (MFMA) ----------------
// Out[row=(b,s)][col=(h,q)] = sum_d X[row][d]*Wt[col][d]; BM=128,BN=128,BK=32
__global__ __launch_bounds__(256) void proj_k(
        const float* __restrict__ q, const float* __restrict__ k, const float* __restrict__ v,
        const u16* __restrict__ Wt_hi, const u16* __restrict__ Wt_lo,
        u16* __restrict__ Qh, u16* __restrict__ Ql,
        u16* __restrict__ Kh, u16* __restrict__ Kl, u16* __restrict__ Vb) {
    const int z = blockIdx.z;
    const float* X = (z == 0) ? q : ((z == 1) ? k : v);
    const int m0 = blockIdx.x * 128, n0 = blockIdx.y * 128;
    const int t = threadIdx.x, lane = t & 63, wid = t >> 6;
    const int mr = wid >> 1, nc = wid & 1;

    __shared__ u16 Ast[2][2][4096];   // [buf][hi/lo][mt8][g4][r16][8]
    __shared__ u16 Bst[2][2][4096];   // [buf][hi/lo][nt8][g4][c16][8]

    // A staging: thread -> (row, 16 k)
    const int arow = t >> 1, akq = (t & 1) * 16;
    const float* Xrow = X + (long long)(m0 + arow) * DD + akq;
    // B staging: 2 slots
    int bgidx[2], bslot[2];
#pragma unroll
    for (int i = 0; i < 2; ++i) {
        int s = t + i * 256;
        int n = s >> 2, g = s & 3;
        int col = n0 + n, hh = col >> 6, qq = col & 63;
        bgidx[i] = ((z * HH + hh) * DQQ + qq) * DD + g * 8;
        bslot[i] = (n >> 4) * 512 + g * 128 + (n & 15) * 8;
    }

    f32x4 acc[4][4];
#pragma unroll
    for (int i = 0; i < 4; ++i)
#pragma unroll
        for (int j = 0; j < 4; ++j) acc[i][j] = (f32x4){0.f, 0.f, 0.f, 0.f};

    float4 Areg[4];
    bf16x8 Bh_reg[2], Bl_reg[2];

    auto loadAB = [&](int k0) {
#pragma unroll
        for (int j = 0; j < 4; ++j)
            Areg[j] = reinterpret_cast<const float4*>(Xrow + k0)[j];
#pragma unroll
        for (int i = 0; i < 2; ++i) {
            Bh_reg[i] = *reinterpret_cast<const bf16x8*>(&Wt_hi[bgidx[i] + k0]);
            if (z < 2) Bl_reg[i] = *reinterpret_cast<const bf16x8*>(&Wt_lo[bgidx[i] + k0]);
        }
    };
    auto stageAB = [&](int buf) {
#pragma unroll
        for (int j = 0; j < 4; ++j) {
            float4 xv = Areg[j];
            const int kk = akq + 4 * j;
            const int off = (arow >> 4) * 512 + (kk >> 3) * 128 + (arow & 15) * 8 + (kk & 7);
            u32 u0 = __float_as_uint(xv.x), u1 = __float_as_uint(xv.y),
                u2 = __float_as_uint(xv.z), u3 = __float_as_uint(xv.w);
            uint2 hp;
            hp.x = (u0 >> 16) | (u1 & 0xFFFF0000u);
            hp.y = (u2 >> 16) | (u3 & 0xFFFF0000u);
            *reinterpret_cast<uint2*>(&Ast[buf][0][off]) = hp;
            if (z < 2) {
                float r0 = xv.x - __uint_as_float(u0 & 0xFFFF0000u);
                float r1 = xv.y - __uint_as_float(u1 & 0xFFFF0000u);
                float r2 = xv.z - __uint_as_float(u2 & 0xFFFF0000u);
                float r3 = xv.w - __uint_as_float(u3 & 0xFFFF0000u);
                uint2 lp;
                lp.x = (u32)bfrne(r0) | ((u32)bfrne(r1) << 16);
                lp.y = (u32)bfrne(r2) | ((u32)bfrne(r3) << 16);
                *reinterpret_cast<uint2*>(&Ast[buf][1][off]) = lp;
            }
        }
#pragma unroll
        for (int i = 0; i < 2; ++i) {
            *reinterpret_cast<bf16x8*>(&Bst[buf][0][bslot[i]]) = Bh_reg[i];
            if (z < 2) *reinterpret_cast<bf16x8*>(&Bst[buf][1][bslot[i]]) = Bl_reg[i];
        }
    };

    loadAB(0);
    stageAB(0);

    for (int c = 0; c < 32; ++c) {
        const int cur = c & 1;
        __syncthreads();
        if (c + 1 < 32) loadAB((c + 1) * 32);

        bf16x8 ah[4], al[4], bh[4], bl[4];
#pragma unroll
        for (int i = 0; i < 4; ++i) {
            ah[i] = *reinterpret_cast<const bf16x8*>(&Ast[cur][0][(mr * 4 + i) * 512 + lane * 8]);
            bh[i] = *reinterpret_cast<const bf16x8*>(&Bst[cur][0][(nc * 4 + i) * 512 + lane * 8]);
            if (z < 2) {
                al[i] = *reinterpret_cast<const bf16x8*>(&Ast[cur][1][(mr * 4 + i) * 512 + lane * 8]);
                bl[i] = *reinterpret_cast<const bf16x8*>(&Bst[cur][1][(nc * 4 + i) * 512 + lane * 8]);
            }
        }
#pragma unroll
        for (int mt = 0; mt < 4; ++mt)
#pragma unroll
            for (int nt = 0; nt < 4; ++nt) {
                acc[mt][nt] = MFMA16(ah[mt], bh[nt], acc[mt][nt]);
                if (z < 2) {
                    acc[mt][nt] = MFMA16(ah[mt], bl[nt], acc[mt][nt]);
                    acc[mt][nt] = MFMA16(al[mt], bh[nt], acc[mt][nt]);
                }
            }
        if (c + 1 < 32) stageAB(cur ^ 1);
    }

    // epilogue
#pragma unroll
    for (int mt = 0; mt < 4; ++mt)
#pragma unroll
        for (int nt = 0; nt < 4; ++nt)
#pragma unroll
            for (int r = 0; r < 4; ++r) {
                int row = m0 + mr * 64 + mt * 16 + (lane >> 4) * 4 + r;
                int col = n0 + nc * 64 + nt * 16 + (lane & 15);
                int bb = row >> 11, ss = row & 2047, hh = col >> 6, qq = col & 63;
                long long idx = ((long long)(bb * HH + hh) * SS + ss) * DQQ + qq;
                float x = acc[mt][nt][r];
                if (z == 2) {
                    Vb[idx] = bfrne(x);
                } else {
                    u32 u = __float_as_uint(x);
                    u16 hi = (u16)(u >> 16);
                    float rres = x - __uint_as_float(u & 0xFFFF0000u);
                    u16 lo = bfrne(rres);
                    if (z == 0) { Qh[idx] = hi; Ql[idx] = lo; }
                    else        { Kh[idx] = hi; Kl[idx] = lo; }
                }
            }
}

// ---------------- fused scores + online softmax diag + output ----------------
// block: (q-tile 128, h, b); 4 waves; K streamed in 64-key chunks.
__global__ __launch_bounds__(256) void attn_k(
        const u16* __restrict__ Qh, const u16* __restrict__ Ql,
        const u16* __restrict__ Kh, const u16* __restrict__ Kl,
        const u16* __restrict__ Vb, const u32* __restrict__ bits,
        float* __restrict__ out) {
    const int qt = blockIdx.x, h = blockIdx.y, b = blockIdx.z;
    const int s0 = qt * 128;
    const long long bh = b * HH + h;
    const int t = threadIdx.x, lane = t & 63, wid = t >> 6;

    __shared__ u16 Kst[2][2][4096];   // [buf][hi/lo][nt4][ks2][g4][c16][8]
    __shared__ float sdiag[128];
    __shared__ float dwgt[128];

    // Q fragments in registers: [mt][ks]
    bf16x8 qfh[2][2], qfl[2][2];
#pragma unroll
    for (int mt = 0; mt < 2; ++mt)
#pragma unroll
        for (int ks = 0; ks < 2; ++ks) {
            int row = s0 + wid * 32 + mt * 16 + (lane & 15);
            long long gi = (bh * SS + row) * DQQ + ks * 32 + (lane >> 4) * 8;
            qfh[mt][ks] = *reinterpret_cast<const bf16x8*>(&Qh[gi]);
            qfl[mt][ks] = *reinterpret_cast<const bf16x8*>(&Ql[gi]);
        }

    // K staging: 2 slots per thread per array
    const int srow0 = t >> 3, su = t & 7;
    const int sks = su >> 2, sg = su & 3;
    int soff[2];
#pragma unroll
    for (int i = 0; i < 2; ++i) {
        int sr = srow0 + i * 32;
        soff[i] = (sr >> 4) * 1024 + sks * 512 + sg * 128 + (sr & 15) * 8;
    }
    bf16x8 sh[2], sl[2];
    auto loadK = [&](int cchN) {
#pragma unroll
        for (int i = 0; i < 2; ++i) {
            long long gi = (bh * SS + cchN * 64 + srow0 + i * 32) * (long long)DQQ + sks * 32 + sg * 8;
            sh[i] = *reinterpret_cast<const bf16x8*>(&Kh[gi]);
            sl[i] = *reinterpret_cast<const bf16x8*>(&Kl[gi]);
        }
    };
    auto stageK = [&](int buf) {
#pragma unroll
        for (int i = 0; i < 2; ++i) {
            *reinterpret_cast<bf16x8*>(&Kst[buf][0][soff[i]]) = sh[i];
            *reinterpret_cast<bf16x8*>(&Kst[buf][1][soff[i]]) = sl[i];
        }
    };

    loadK(0);
    stageK(0);

    float mrun[2][4], srun[2][4];
#pragma unroll
    for (int mt = 0; mt < 2; ++mt)
#pragma unroll
        for (int r = 0; r < 4; ++r) { mrun[mt][r] = -INFINITY; srun[mt][r] = 0.f; }

    const int cc0 = s0 >> 6;

    for (int cch = 0; cch < 32; ++cch) {
        const int cur = cch & 1;
        const int t0 = cch * 64;
        __syncthreads();
        if (cch + 1 < 32) loadK(cch + 1);

        // mask words (issued early; L1-resident)
        u32 mw0[2][4], mw1[2][4];
#pragma unroll
        for (int mt = 0; mt < 2; ++mt)
#pragma unroll
            for (int r = 0; r < 4; ++r) {
                long long mi = ((long long)(b * SS) + s0 + wid * 32 + mt * 16 + (lane >> 4) * 4 + r) * 64 + cch * 2;
                mw0[mt][r] = bits[mi];
                mw1[mt][r] = bits[mi + 1];
            }

        bf16x8 kfh[4][2], kfl[4][2];
#pragma unroll
        for (int nt = 0; nt < 4; ++nt)
#pragma unroll
            for (int ks = 0; ks < 2; ++ks) {
                kfh[nt][ks] = *reinterpret_cast<const bf16x8*>(&Kst[cur][0][nt * 1024 + ks * 512 + lane * 8]);
                kfl[nt][ks] = *reinterpret_cast<const bf16x8*>(&Kst[cur][1][nt * 1024 + ks * 512 + lane * 8]);
            }

        f32x4 sc[2][4];
        const f32x4 zz = (f32x4){0.f, 0.f, 0.f, 0.f};
#pragma unroll
        for (int mt = 0; mt < 2; ++mt)
#pragma unroll
            for (int nt = 0; nt < 4; ++nt) {
                f32x4 a = MFMA16(qfh[mt][0], kfh[nt][0], zz);
                a = MFMA16(qfh[mt][1], kfh[nt][1], a);
                a = MFMA16(qfh[mt][0], kfl[nt][0], a);
                a = MFMA16(qfh[mt][1], kfl[nt][1], a);
                a = MFMA16(qfl[mt][0], kfh[nt][0], a);
                a = MFMA16(qfl[mt][1], kfh[nt][1], a);
                sc[mt][nt] = a;
            }

        const bool dchunk = (cch == cc0) || (cch == cc0 + 1);
#pragma unroll
        for (int mt = 0; mt < 2; ++mt)
#pragma unroll
            for (int r = 0; r < 4; ++r) {
                float v[4];
                u32 w0 = mw0[mt][r], w1 = mw1[mt][r];
#pragma unroll
                for (int nt = 0; nt < 4; ++nt) {
                    u32 w = (nt < 2) ? w0 : w1;
                    u32 bit = (w >> ((nt & 1) * 16 + (lane & 15))) & 1u;
                    v[nt] = bit ? sc[mt][nt][r] * SCALE : NEG9;
                }
                if (dchunk) {
                    int sl_ = wid * 32 + mt * 16 + (lane >> 4) * 4 + r;
                    int cd = s0 + sl_ - t0;
#pragma unroll
                    for (int nt = 0; nt < 4; ++nt)
                        if (cd >= 0 && cd < 64 && (cd >> 4) == nt && (cd & 15) == (lane & 15))
                            sdiag[sl_] = v[nt];
                }
                float vmax = fmaxf(fmaxf(v[0], v[1]), fmaxf(v[2], v[3]));
                float mo = mrun[mt][r];
                float mn = fmaxf(mo, vmax);
                float ssum = __expf(v[0] - mn) + __expf(v[1] - mn) +
                             __expf(v[2] - mn) + __expf(v[3] - mn);
                srun[mt][r] = srun[mt][r] * __expf(mo - mn) + ssum;
                mrun[mt][r] = mn;
            }

        if (cch + 1 < 32) stageK(cur ^ 1);
    }

    // merge (m,sum) across the 16 lanes of each row group
#pragma unroll
    for (int mt = 0; mt < 2; ++mt)
#pragma unroll
        for (int r = 0; r < 4; ++r) {
            float mo = mrun[mt][r], so = srun[mt][r];
#pragma unroll
            for (int st = 1; st < 16; st <<= 1) {
                float m2 = __shfl_xor(mo, st, 64);
                float s2 = __shfl_xor(so, st, 64);
                float mn = fmaxf(mo, m2);
                so = so * __expf(mo - mn) + s2 * __expf(m2 - mn);
                mo = mn;
            }
            if ((lane & 15) == 0) {
                int sl_ = wid * 32 + mt * 16 + (lane >> 4) * 4 + r;
                dwgt[sl_] = __expf(sdiag[sl_] - mo) / so;
            }
        }
    __syncthreads();

    // output: out[row] = dwgt[row] * V[row]
    const int orow = t >> 1, oc = (t & 1) * 32;
    const float w = dwgt[orow];
    const u16* vp = Vb + (bh * SS + s0 + orow) * DQQ + oc;
    float* op = out + (bh * SS + s0 + orow) * DQQ + oc;
#pragma unroll
    for (int j = 0; j < 4; ++j) {
        bf16x8 vv = *reinterpret_cast<const bf16x8*>(&vp[j * 8]);
        float4 o0, o1;
        o0.x = __uint_as_float(((u32)(u16)vv[0]) << 16) * w;
        o0.y = __uint_as_float(((u32)(u16)vv[1]) << 16) * w;
        o0.z = __uint_as_float(((u32)(u16)vv[2]) << 16) * w;
        o0.w = __uint_as_float(((u32)(u16)vv[3]) << 16) * w;
        o1.x = __uint_as_float(((u32)(u16)vv[4]) << 16) * w;
        o1.y = __uint_as_float(((u32)(u16)vv[5]) << 16) * w;
        o1.z = __uint_as_float(((u32)(u16)vv[6]) << 16) * w;
        o1.w = __uint_as_float(((u32)(u16)vv[7]) << 16) * w;
        reinterpret_cast<float4*>(op)[2 * j] = o0;
        reinterpret_cast<float4*>(op)[2 * j + 1] = o1;
    }
}

extern "C" void kernel_launch(void* const* d_in, const int* in_sizes, int n_in,
                              void* d_out, int out_size, void* d_ws, size_t ws_size,
                              hipStream_t stream) {
    (void)in_sizes; (void)n_in; (void)out_size; (void)ws_size;
    const float* q    = (const float*)d_in[0];
    const float* k    = (const float*)d_in[1];
    const float* v    = (const float*)d_in[2];
    const int*   mask = (const int*)d_in[3];
    const float* wq   = (const float*)d_in[4];
    const float* wk   = (const float*)d_in[5];
    const float* wv   = (const float*)d_in[6];

    const size_t NP = (size_t)BB * HH * SS * DQQ;       // 8388608
    char* wsp = (char*)d_ws;
    u16* Qh = (u16*)wsp;                 wsp += NP * 2;
    u16* Ql = (u16*)wsp;                 wsp += NP * 2;
    u16* Kh = (u16*)wsp;                 wsp += NP * 2;
    u16* Kl = (u16*)wsp;                 wsp += NP * 2;
    u16* Vb = (u16*)wsp;                 wsp += NP * 2;
    u16* Wt_hi = (u16*)wsp;              wsp += (size_t)3 * HH * DQQ * DD * 2;
    u16* Wt_lo = (u16*)wsp;              wsp += (size_t)3 * HH * DQQ * DD * 2;
    u32* bits = (u32*)wsp;

    mask_pack_k<<<dim3((BB * SS * 64) / 256), dim3(256), 0, stream>>>(mask, bits);
    wsplit_k<<<dim3(16, 16, 3), dim3(256), 0, stream>>>(wq, wk, wv, Wt_hi, Wt_lo);
    proj_k<<<dim3(64, 8, 3), dim3(256), 0, stream>>>(q, k, v, Wt_hi, Wt_lo,
                                                     Qh, Ql, Kh, Kl, Vb);
    attn_k<<<dim3(16, 16, 4), dim3(256), 0, stream>>>(Qh, Ql, Kh, Kl, Vb, bits,
                                                      (float*)d_out);
}